// Round 6
// baseline (467.949 us; speedup 1.0000x reference)
//
#include <hip/hip_runtime.h>
#include <stdint.h>

typedef unsigned short ushort_t;
typedef __attribute__((ext_vector_type(8))) short short8;
typedef __attribute__((ext_vector_type(4))) float floatx4;

#define B_   8192
#define IN_  1024
#define H_   1024

#define WB_ELEMS   (H_ * IN_)            // 1048576
// ws layout (ushort elements): Wb[8][1M]  (slots: i,f,g,o x-weights then i,f,g,o h-weights)

__device__ __forceinline__ ushort_t f2bf(float f) {
    union { float f; uint32_t i; } v; v.f = f;
    uint32_t r = (v.i + 0x7fffu + ((v.i >> 16) & 1u)) >> 16;
    return (ushort_t)r;
}
__device__ __forceinline__ float sigmoid_(float x) {
    return 1.0f / (1.0f + __expf(-x));
}
__device__ __forceinline__ float tanh_(float x) {
    float xc = fminf(fmaxf(x, -20.f), 20.f);
    float e = __expf(2.f * xc);
    return (e - 1.f) / (e + 1.f);
}

// async global->LDS DMA, 16B per lane; dest is wave-uniform base + lane*16.
__device__ __forceinline__ void gll16(const void* gsrc, void* ldst) {
    __builtin_amdgcn_global_load_lds(
        (const __attribute__((address_space(1))) void*)gsrc,
        (__attribute__((address_space(3))) void*)ldst,
        16, 0, 0);
}

// ---- prep: f32 -> bf16 for the 8 weight matrices only (x/h stay f32) ----
__global__ __launch_bounds__(256) void cvt_w_kernel(
    const float* __restrict__ Wix, const float* __restrict__ Wfx,
    const float* __restrict__ Wgx, const float* __restrict__ Wox,
    const float* __restrict__ Wih, const float* __restrict__ Wfh,
    const float* __restrict__ Wgh, const float* __restrict__ Woh,
    ushort_t* __restrict__ ws)
{
    const int c = blockIdx.x * 256 + threadIdx.x;   // 1M chunks of 8 elems
    const int s = c >> 17;                          // weight slot 0..7
    const float* src =
        s == 0 ? Wix : s == 1 ? Wfx : s == 2 ? Wgx : s == 3 ? Wox :
        s == 4 ? Wih : s == 5 ? Wfh : s == 6 ? Wgh : Woh;
    ushort_t* dst = ws + (size_t)s * WB_ELEMS;
    const int off = (c & 131071) * 8;
    float4 f0 = *(const float4*)(src + off);
    float4 f1 = *(const float4*)(src + off + 4);
    short8 o;
    o[0] = (short)f2bf(f0.x); o[1] = (short)f2bf(f0.y);
    o[2] = (short)f2bf(f0.z); o[3] = (short)f2bf(f0.w);
    o[4] = (short)f2bf(f1.x); o[5] = (short)f2bf(f1.y);
    o[6] = (short)f2bf(f1.z); o[7] = (short)f2bf(f1.w);
    *(short8*)(dst + off) = o;
}

// Tile: 128 batch rows x (32 hidden cols x 4 gates = 128 virtual cols), BK=32.
// A staged as FLOAT32 straight from d_in via gll16 (swizzled: lane fetches
// logical k-chunk c=(p-row)&7 so physical layout is XOR-swizzled -> 2-way
// (free) bank conflicts despite 128B rows). Frags truncate-packed to bf16.
// B (weights) staged bf16 via gll16, swizzled c=(p-(row>>1))&3.
// Outputs FLOAT32: h_next [8M] then c_next [8M].
__global__ __launch_bounds__(256) void lstm_cell_kernel(
    const float* __restrict__ Xf,  const float* __restrict__ Hf,
    const ushort_t* __restrict__ Wb,  // 8 slots of [H][K] bf16
    const float* __restrict__ Cprev,
    const float* __restrict__ Bi, const float* __restrict__ Bf,
    const float* __restrict__ Bg, const float* __restrict__ Bo,
    float* __restrict__ Out)
{
    __shared__ __align__(16) float    Asf[128 * 32];   // 16 KB, f32, swizzled
    __shared__ __align__(16) ushort_t Bs [128 * 32];   // 8 KB, bf16, swizzled

    const int t   = threadIdx.x;
    const int bm0 = blockIdx.y * 128;
    const int j0  = blockIdx.x * 32;

    // ---- A staging: 1024 16B-chunks (4/thread). phys (row,p) holds logical
    // k-chunk c=(p-row)&7 -> lane idx fetches global chunk c. ----
    size_t offA[4];
    #pragma unroll
    for (int i = 0; i < 4; ++i) {
        const int idx = t + 256 * i;
        const int r = idx >> 3, p = idx & 7;
        const int c = (p - r) & 7;
        offA[i] = (size_t)(bm0 + r) * IN_ + c * 4;
    }

    // ---- B staging: 512 16B-chunks (2/thread). virtual row v -> gate (v>>4)&3,
    // j = j0 + (v>>6)*16 + (v&15); phys chunk p holds c=(p-(v>>1))&3. ----
    const int idx0 = t, idx1 = t + 256;
    const int vr0 = idx0 >> 2, pB0 = idx0 & 3, cB0 = (pB0 - (vr0 >> 1)) & 3;
    const int vr1 = idx1 >> 2, pB1 = idx1 & 3, cB1 = (pB1 - (vr1 >> 1)) & 3;
    const int g0 = (vr0 >> 4) & 3, g1 = (vr1 >> 4) & 3;
    const int jj0_ = j0 + ((vr0 >> 6) << 4) + (vr0 & 15);
    const int jj1_ = j0 + ((vr1 >> 6) << 4) + (vr1 & 15);
    const ushort_t* wx0 = Wb + (size_t)g0 * WB_ELEMS + (size_t)jj0_ * IN_ + cB0 * 8;
    const ushort_t* wx1 = Wb + (size_t)g1 * WB_ELEMS + (size_t)jj1_ * IN_ + cB1 * 8;
    const ushort_t* wh0 = Wb + (size_t)(4 + g0) * WB_ELEMS + (size_t)jj0_ * H_ + cB0 * 8;
    const ushort_t* wh1 = Wb + (size_t)(4 + g1) * WB_ELEMS + (size_t)jj1_ * H_ + cB1 * 8;

    float*    ldsA0 = &Asf[(t      ) * 4];
    float*    ldsA1 = &Asf[(t + 256) * 4];
    float*    ldsA2 = &Asf[(t + 512) * 4];
    float*    ldsA3 = &Asf[(t + 768) * 4];
    ushort_t* ldsB0 = &Bs[idx0 * 8];
    ushort_t* ldsB1 = &Bs[idx1 * 8];

    // ---- compute-side fragment addressing ----
    const int lane = t & 63;
    const int w = t >> 6;
    const int lr = lane & 15, lk = lane >> 4;
    const int rowbase = (w >> 1) * 64;
    const int colhalf = w & 1;

    floatx4 acc[4][4] = {};   // [row-tile][gate]

    for (int phase = 0; phase < 2; ++phase) {
        const float* abase = phase ? Hf : Xf;
        const ushort_t* b0 = phase ? wh0 : wx0;
        const ushort_t* b1 = phase ? wh1 : wx1;
        for (int k0 = 0; k0 < 1024; k0 += 32) {
            gll16(abase + offA[0] + k0, ldsA0);
            gll16(abase + offA[1] + k0, ldsA1);
            gll16(abase + offA[2] + k0, ldsA2);
            gll16(abase + offA[3] + k0, ldsA3);
            gll16(b0, ldsB0);
            gll16(b1, ldsB1);
            b0 += 32; b1 += 32;
            __syncthreads();   // vmcnt(0) drain -> DMA complete

            short8 af[4], bfr[4];
            #pragma unroll
            for (int rt = 0; rt < 4; ++rt) {
                const int r = rowbase + rt * 16 + lr;
                const int p0 = (lk * 2 + r) & 7;
                const int p1 = (lk * 2 + 1 + r) & 7;
                union { float4 f; uint4 u; } q0, q1;
                q0.f = *(const float4*)(&Asf[r * 32 + p0 * 4]);   // k = lk*8 .. +3
                q1.f = *(const float4*)(&Asf[r * 32 + p1 * 4]);   // k = lk*8+4 .. +7
                union { uint32_t u[4]; short8 s; } pk;
                pk.u[0] = (q0.u.y & 0xffff0000u) | (q0.u.x >> 16);
                pk.u[1] = (q0.u.w & 0xffff0000u) | (q0.u.z >> 16);
                pk.u[2] = (q1.u.y & 0xffff0000u) | (q1.u.x >> 16);
                pk.u[3] = (q1.u.w & 0xffff0000u) | (q1.u.z >> 16);
                af[rt] = pk.s;
            }
            #pragma unroll
            for (int ct = 0; ct < 4; ++ct) {
                const int vr = colhalf * 64 + ct * 16 + lr;
                const int p = (lk + (vr >> 1)) & 3;
                bfr[ct] = *(const short8*)(&Bs[vr * 32 + p * 8]);
            }
            #pragma unroll
            for (int rt = 0; rt < 4; ++rt)
                #pragma unroll
                for (int ct = 0; ct < 4; ++ct)
                    acc[rt][ct] = __builtin_amdgcn_mfma_f32_16x16x32_bf16(
                        af[rt], bfr[ct], acc[rt][ct], 0, 0, 0);
            __syncthreads();   // frag reads done before next DMA overwrite
        }
    }

    // ---- epilogue: 4 gates live in acc[rt][0..3], same lane/reg ----
    const int j = j0 + colhalf * 16 + lr;
    const float bi = Bi[j], bff = Bf[j], bg = Bg[j], bo = Bo[j];

    #pragma unroll
    for (int rt = 0; rt < 4; ++rt) {
        #pragma unroll
        for (int reg = 0; reg < 4; ++reg) {
            const int m = bm0 + rowbase + rt * 16 + lk * 4 + reg;
            const float zi = acc[rt][0][reg] + bi;
            const float zf = acc[rt][1][reg] + bff;
            const float zg = acc[rt][2][reg] + bg;
            const float zo = acc[rt][3][reg] + bo;
            const float ig = sigmoid_(zi);
            const float fg = sigmoid_(zf);
            const float gg = tanh_(zg);
            const float og = sigmoid_(zo);
            const float cp = Cprev[(size_t)m * H_ + j];
            const float cn = fg * cp + ig * gg;
            const float hn = og * tanh_(cn);
            Out[(size_t)m * H_ + j] = hn;                             // h_next (f32)
            Out[(size_t)B_ * H_ + (size_t)m * H_ + j] = cn;           // c_next (f32)
        }
    }
}

extern "C" void kernel_launch(void* const* d_in, const int* in_sizes, int n_in,
                              void* d_out, int out_size, void* d_ws, size_t ws_size,
                              hipStream_t stream)
{
    (void)in_sizes; (void)n_in; (void)out_size; (void)ws_size;
    const float* X   = (const float*)d_in[0];
    const float* Hin = (const float*)d_in[1];
    const float* Cp  = (const float*)d_in[2];
    const float* Wfx = (const float*)d_in[3];
    const float* Bf  = (const float*)d_in[4];
    const float* Wfh = (const float*)d_in[5];
    const float* Wix = (const float*)d_in[6];
    const float* Bi  = (const float*)d_in[7];
    const float* Wih = (const float*)d_in[8];
    const float* Wgx = (const float*)d_in[9];
    const float* Bg  = (const float*)d_in[10];
    const float* Wgh = (const float*)d_in[11];
    const float* Wox = (const float*)d_in[12];
    const float* Bo  = (const float*)d_in[13];
    const float* Woh = (const float*)d_in[14];
    float* Out = (float*)d_out;
    ushort_t* ws  = (ushort_t*)d_ws;

    // prep: f32 -> bf16 weights only (8M elems)
    cvt_w_kernel<<<dim3(4096), dim3(256), 0, stream>>>(
        Wix, Wfx, Wgx, Wox, Wih, Wfh, Wgh, Woh, ws);

    dim3 grid(H_ / 32, B_ / 128);   // 32 x 64 = 2048 blocks
    lstm_cell_kernel<<<grid, dim3(256), 0, stream>>>(
        X, Hin, ws, Cp, Bi, Bf, Bg, Bo, Out);
}

// Round 7
// 349.295 us; speedup vs baseline: 1.3397x; 1.3397x over previous
//
#include <hip/hip_runtime.h>
#include <stdint.h>

typedef unsigned short ushort_t;
typedef __attribute__((ext_vector_type(8))) short short8;
typedef __attribute__((ext_vector_type(4))) float floatx4;

#define B_   8192
#define IN_  1024
#define H_   1024

#define XB_ELEMS   (B_ * IN_)            // 8388608
#define WB_ELEMS   (H_ * IN_)            // 1048576
// ws layout (ushort elements): Xb[8M] | Hb[8M] | Wb[8][1M]  (slots: i,f,g,o x-wts then i,f,g,o h-wts)
#define WS_XB   0
#define WS_HB   XB_ELEMS
#define WS_WB   (2 * XB_ELEMS)

__device__ __forceinline__ ushort_t f2bf(float f) {
    union { float f; uint32_t i; } v; v.f = f;
    uint32_t r = (v.i + 0x7fffu + ((v.i >> 16) & 1u)) >> 16;
    return (ushort_t)r;
}
__device__ __forceinline__ float sigmoid_(float x) {
    return 1.0f / (1.0f + __expf(-x));
}
__device__ __forceinline__ float tanh_(float x) {
    float xc = fminf(fmaxf(x, -20.f), 20.f);
    float e = __expf(2.f * xc);
    return (e - 1.f) / (e + 1.f);
}

// async global->LDS DMA, 16B/lane; dest must be wave-uniform base + lane*16.
__device__ __forceinline__ void gll16(const ushort_t* gsrc, ushort_t* ldst) {
    __builtin_amdgcn_global_load_lds(
        (const __attribute__((address_space(1))) void*)gsrc,
        (__attribute__((address_space(3))) void*)ldst,
        16, 0, 0);
}

// ---- prep: f32 -> bf16 for x, h, 8 weight matrices into ws (round-5 proven) ----
__global__ __launch_bounds__(256) void cvt_kernel(
    const float* __restrict__ X,   const float* __restrict__ Hin,
    const float* __restrict__ Wix, const float* __restrict__ Wfx,
    const float* __restrict__ Wgx, const float* __restrict__ Wox,
    const float* __restrict__ Wih, const float* __restrict__ Wfh,
    const float* __restrict__ Wgh, const float* __restrict__ Woh,
    ushort_t* __restrict__ ws)
{
    const int c = blockIdx.x * 256 + threadIdx.x;
    const float* src;
    ushort_t* dst;
    int off;
    if (c < 2097152) {
        const int t = c >> 20;                 // 0 = x, 1 = h
        src = t ? Hin : X;
        dst = ws + (t ? WS_HB : WS_XB);
        off = (c & 1048575) * 8;
    } else {
        const int cc = c - 2097152;
        const int s = cc >> 17;                // weight slot 0..7
        const float* w =
            s == 0 ? Wix : s == 1 ? Wfx : s == 2 ? Wgx : s == 3 ? Wox :
            s == 4 ? Wih : s == 5 ? Wfh : s == 6 ? Wgh : Woh;
        src = w;
        dst = ws + WS_WB + s * WB_ELEMS;
        off = (cc & 131071) * 8;
    }
    float4 f0 = *(const float4*)(src + off);
    float4 f1 = *(const float4*)(src + off + 4);
    short8 o;
    o[0] = (short)f2bf(f0.x); o[1] = (short)f2bf(f0.y);
    o[2] = (short)f2bf(f0.z); o[3] = (short)f2bf(f0.w);
    o[4] = (short)f2bf(f1.x); o[5] = (short)f2bf(f1.y);
    o[6] = (short)f2bf(f1.z); o[7] = (short)f2bf(f1.w);
    *(short8*)(dst + off) = o;
}

// Round-5 structure (bf16 gll16 staging) with BK=64: 32 KB LDS, 32 iterations
// total (2 phases x 16), 32 MFMA per barrier-pair -> half the barrier drains.
// Tile: 128 batch rows x (32 j x 4 gates = 128 virtual cols).
// Wave w: rows (w>>1)*64, col-half (w&1); 4 col-tiles = 4 gates at one j range.
// Outputs FLOAT32: h_next [8M] then c_next [8M].
__global__ __launch_bounds__(256) void lstm_cell_kernel(
    const ushort_t* __restrict__ Xb,  const ushort_t* __restrict__ Hb,
    const ushort_t* __restrict__ Wb,  // 8 slots of [H][K] bf16
    const float* __restrict__ Cprev,
    const float* __restrict__ Bi, const float* __restrict__ Bf,
    const float* __restrict__ Bg, const float* __restrict__ Bo,
    float* __restrict__ Out)
{
    __shared__ __align__(16) ushort_t As[128 * 64];   // 16 KB
    __shared__ __align__(16) ushort_t Bs[128 * 64];   // 16 KB

    const int t   = threadIdx.x;
    const int bm0 = blockIdx.y * 128;
    const int j0  = blockIdx.x * 32;

    // ---- staging: 1024 16B-chunks per tile, 4 per thread; 8 chunks per row ----
    int rA[4], kcA[4];
    const ushort_t* wxp[4];
    const ushort_t* whp[4];
    ushort_t *ldsA[4], *ldsB[4];
    #pragma unroll
    for (int i = 0; i < 4; ++i) {
        const int idx = t + 256 * i;
        rA[i]  = idx >> 3;            // 0..127
        kcA[i] = (idx & 7) * 8;       // k offset within BK=64
        ldsA[i] = &As[idx * 8];
        ldsB[i] = &Bs[idx * 8];
        // B: virtual row v -> gate (v>>4)&3, j = j0 + (v>>6)*16 + (v&15)
        const int v = rA[i];
        const int g = (v >> 4) & 3;
        const int jj = j0 + ((v >> 6) << 4) + (v & 15);
        wxp[i] = Wb + (size_t)g * WB_ELEMS + (size_t)jj * IN_ + kcA[i];
        whp[i] = Wb + (size_t)(4 + g) * WB_ELEMS + (size_t)jj * H_ + kcA[i];
    }

    // ---- compute-side fragment addressing ----
    const int lane = t & 63;
    const int w = t >> 6;
    const int lr = lane & 15, lk = lane >> 4;
    const int rowbase = (w >> 1) * 64;
    const int colhalf = w & 1;

    floatx4 acc[4][4] = {};   // [row-tile][gate]

    for (int phase = 0; phase < 2; ++phase) {
        const ushort_t* abase = phase ? Hb : Xb;
        const ushort_t* a0 = abase + (size_t)(bm0 + rA[0]) * IN_ + kcA[0];
        const ushort_t* a1 = abase + (size_t)(bm0 + rA[1]) * IN_ + kcA[1];
        const ushort_t* a2 = abase + (size_t)(bm0 + rA[2]) * IN_ + kcA[2];
        const ushort_t* a3 = abase + (size_t)(bm0 + rA[3]) * IN_ + kcA[3];
        const ushort_t* b0 = phase ? whp[0] : wxp[0];
        const ushort_t* b1 = phase ? whp[1] : wxp[1];
        const ushort_t* b2 = phase ? whp[2] : wxp[2];
        const ushort_t* b3 = phase ? whp[3] : wxp[3];
        for (int k0 = 0; k0 < 1024; k0 += 64) {
            gll16(a0, ldsA[0]); gll16(a1, ldsA[1]);
            gll16(a2, ldsA[2]); gll16(a3, ldsA[3]);
            gll16(b0, ldsB[0]); gll16(b1, ldsB[1]);
            gll16(b2, ldsB[2]); gll16(b3, ldsB[3]);
            a0 += 64; a1 += 64; a2 += 64; a3 += 64;
            b0 += 64; b1 += 64; b2 += 64; b3 += 64;
            __syncthreads();   // vmcnt(0) drain -> DMA complete

            #pragma unroll
            for (int ks = 0; ks < 2; ++ks) {
                short8 af[4], bfr[4];
                #pragma unroll
                for (int rt = 0; rt < 4; ++rt)
                    af[rt] = *(const short8*)(
                        &As[(rowbase + rt * 16 + lr) * 64 + ks * 32 + lk * 8]);
                #pragma unroll
                for (int ct = 0; ct < 4; ++ct)
                    bfr[ct] = *(const short8*)(
                        &Bs[(colhalf * 64 + ct * 16 + lr) * 64 + ks * 32 + lk * 8]);
                #pragma unroll
                for (int rt = 0; rt < 4; ++rt)
                    #pragma unroll
                    for (int ct = 0; ct < 4; ++ct)
                        acc[rt][ct] = __builtin_amdgcn_mfma_f32_16x16x32_bf16(
                            af[rt], bfr[ct], acc[rt][ct], 0, 0, 0);
            }
            __syncthreads();   // frag reads done before next DMA overwrite
        }
    }

    // ---- epilogue: 4 gates live in acc[rt][0..3], same lane/reg ----
    const int j = j0 + colhalf * 16 + lr;
    const float bi = Bi[j], bff = Bf[j], bg = Bg[j], bo = Bo[j];

    #pragma unroll
    for (int rt = 0; rt < 4; ++rt) {
        #pragma unroll
        for (int reg = 0; reg < 4; ++reg) {
            const int m = bm0 + rowbase + rt * 16 + lk * 4 + reg;
            const float zi = acc[rt][0][reg] + bi;
            const float zf = acc[rt][1][reg] + bff;
            const float zg = acc[rt][2][reg] + bg;
            const float zo = acc[rt][3][reg] + bo;
            const float ig = sigmoid_(zi);
            const float fg = sigmoid_(zf);
            const float gg = tanh_(zg);
            const float og = sigmoid_(zo);
            const float cp = Cprev[(size_t)m * H_ + j];
            const float cn = fg * cp + ig * gg;
            const float hn = og * tanh_(cn);
            Out[(size_t)m * H_ + j] = hn;                             // h_next (f32)
            Out[(size_t)B_ * H_ + (size_t)m * H_ + j] = cn;           // c_next (f32)
        }
    }
}

extern "C" void kernel_launch(void* const* d_in, const int* in_sizes, int n_in,
                              void* d_out, int out_size, void* d_ws, size_t ws_size,
                              hipStream_t stream)
{
    (void)in_sizes; (void)n_in; (void)out_size; (void)ws_size;
    const float* X   = (const float*)d_in[0];
    const float* Hin = (const float*)d_in[1];
    const float* Cp  = (const float*)d_in[2];
    const float* Wfx = (const float*)d_in[3];
    const float* Bf  = (const float*)d_in[4];
    const float* Wfh = (const float*)d_in[5];
    const float* Wix = (const float*)d_in[6];
    const float* Bi  = (const float*)d_in[7];
    const float* Wih = (const float*)d_in[8];
    const float* Wgx = (const float*)d_in[9];
    const float* Bg  = (const float*)d_in[10];
    const float* Wgh = (const float*)d_in[11];
    const float* Wox = (const float*)d_in[12];
    const float* Bo  = (const float*)d_in[13];
    const float* Woh = (const float*)d_in[14];
    float* Out = (float*)d_out;
    ushort_t* ws  = (ushort_t*)d_ws;

    // prep: f32 -> bf16 (x, h, 8 weights) into ws
    cvt_kernel<<<dim3(12288), dim3(256), 0, stream>>>(
        X, Hin, Wix, Wfx, Wgx, Wox, Wih, Wfh, Wgh, Woh, ws);

    dim3 grid(H_ / 32, B_ / 128);   // 32 x 64 = 2048 blocks
    lstm_cell_kernel<<<grid, dim3(256), 0, stream>>>(
        ws + WS_XB, ws + WS_HB, ws + WS_WB,
        Cp, Bi, Bf, Bg, Bo, Out);
}

// Round 8
// 319.454 us; speedup vs baseline: 1.4648x; 1.0934x over previous
//
#include <hip/hip_runtime.h>
#include <stdint.h>

typedef unsigned short ushort_t;
typedef __attribute__((ext_vector_type(8))) short short8;
typedef __attribute__((ext_vector_type(4))) float floatx4;

#define B_   8192
#define IN_  1024
#define H_   1024

#define XB_ELEMS   (B_ * IN_)            // 8388608
#define WB_ELEMS   (H_ * IN_)            // 1048576
// ws layout (ushort elements): Xb[8M] | Hb[8M] | Wb[8][1M]  (slots: i,f,g,o x-wts then i,f,g,o h-wts)
#define WS_XB   0
#define WS_HB   XB_ELEMS
#define WS_WB   (2 * XB_ELEMS)

__device__ __forceinline__ ushort_t f2bf(float f) {
    union { float f; uint32_t i; } v; v.f = f;
    uint32_t r = (v.i + 0x7fffu + ((v.i >> 16) & 1u)) >> 16;
    return (ushort_t)r;
}
__device__ __forceinline__ float sigmoid_(float x) {
    return 1.0f / (1.0f + __expf(-x));
}
__device__ __forceinline__ float tanh_(float x) {
    float xc = fminf(fmaxf(x, -20.f), 20.f);
    float e = __expf(2.f * xc);
    return (e - 1.f) / (e + 1.f);
}

// async global->LDS DMA, 16B/lane; dest must be wave-uniform base + lane*16.
__device__ __forceinline__ void gll16(const ushort_t* gsrc, ushort_t* ldst) {
    __builtin_amdgcn_global_load_lds(
        (const __attribute__((address_space(1))) void*)gsrc,
        (__attribute__((address_space(3))) void*)ldst,
        16, 0, 0);
}

// ---- prep: f32 -> bf16 for x, h, 8 weight matrices into ws ----
__global__ __launch_bounds__(256) void cvt_kernel(
    const float* __restrict__ X,   const float* __restrict__ Hin,
    const float* __restrict__ Wix, const float* __restrict__ Wfx,
    const float* __restrict__ Wgx, const float* __restrict__ Wox,
    const float* __restrict__ Wih, const float* __restrict__ Wfh,
    const float* __restrict__ Wgh, const float* __restrict__ Woh,
    ushort_t* __restrict__ ws)
{
    const int c = blockIdx.x * 256 + threadIdx.x;
    const float* src;
    ushort_t* dst;
    int off;
    if (c < 2097152) {
        const int t = c >> 20;                 // 0 = x, 1 = h
        src = t ? Hin : X;
        dst = ws + (t ? WS_HB : WS_XB);
        off = (c & 1048575) * 8;
    } else {
        const int cc = c - 2097152;
        const int s = cc >> 17;                // weight slot 0..7
        const float* w =
            s == 0 ? Wix : s == 1 ? Wfx : s == 2 ? Wgx : s == 3 ? Wox :
            s == 4 ? Wih : s == 5 ? Wfh : s == 6 ? Wgh : Woh;
        src = w;
        dst = ws + WS_WB + s * WB_ELEMS;
        off = (cc & 131071) * 8;
    }
    float4 f0 = *(const float4*)(src + off);
    float4 f1 = *(const float4*)(src + off + 4);
    short8 o;
    o[0] = (short)f2bf(f0.x); o[1] = (short)f2bf(f0.y);
    o[2] = (short)f2bf(f0.z); o[3] = (short)f2bf(f0.w);
    o[4] = (short)f2bf(f1.x); o[5] = (short)f2bf(f1.y);
    o[6] = (short)f2bf(f1.z); o[7] = (short)f2bf(f1.w);
    *(short8*)(dst + off) = o;
}

// BK=64 + XOR-swizzled LDS: phys chunk p of row r holds logical k-chunk
// c = p ^ (r&7). DMA dest stays idx-contiguous (wave-uniform + lane*16);
// the *global* source is permuted instead. Fragment reads then spread the
// 16 lr-lanes over all 8 chunk positions -> 2-way bank aliasing (free).
// Tile: 128 batch rows x (32 j x 4 gates = 128 virtual cols).
// Outputs FLOAT32: h_next [8M] then c_next [8M].
__global__ __launch_bounds__(256) void lstm_cell_kernel(
    const ushort_t* __restrict__ Xb,  const ushort_t* __restrict__ Hb,
    const ushort_t* __restrict__ Wb,  // 8 slots of [H][K] bf16
    const float* __restrict__ Cprev,
    const float* __restrict__ Bi, const float* __restrict__ Bf,
    const float* __restrict__ Bg, const float* __restrict__ Bo,
    float* __restrict__ Out)
{
    __shared__ __align__(16) ushort_t As[128 * 64];   // 16 KB
    __shared__ __align__(16) ushort_t Bs[128 * 64];   // 16 KB

    const int t   = threadIdx.x;
    const int bm0 = blockIdx.y * 128;
    const int j0  = blockIdx.x * 32;

    // ---- staging: 1024 16B-chunks per tile, 4/thread; 8 chunks per row.
    // lane writes phys chunk idx, fetches logical chunk c = (idx&7)^(row&7). ----
    int rA[4], kcA[4];
    const ushort_t* wxp[4];
    const ushort_t* whp[4];
    ushort_t *ldsA[4], *ldsB[4];
    #pragma unroll
    for (int i = 0; i < 4; ++i) {
        const int idx = t + 256 * i;
        rA[i]  = idx >> 3;                       // 0..127
        const int p = idx & 7;
        kcA[i] = (p ^ (rA[i] & 7)) * 8;          // swizzled k offset in BK=64
        ldsA[i] = &As[idx * 8];
        ldsB[i] = &Bs[idx * 8];
        // B: virtual row v -> gate (v>>4)&3, j = j0 + (v>>6)*16 + (v&15)
        const int v = rA[i];
        const int g = (v >> 4) & 3;
        const int jj = j0 + ((v >> 6) << 4) + (v & 15);
        wxp[i] = Wb + (size_t)g * WB_ELEMS + (size_t)jj * IN_ + kcA[i];
        whp[i] = Wb + (size_t)(4 + g) * WB_ELEMS + (size_t)jj * H_ + kcA[i];
    }

    // ---- compute-side fragment addressing ----
    const int lane = t & 63;
    const int w = t >> 6;
    const int lr = lane & 15, lk = lane >> 4;
    const int rowbase = (w >> 1) * 64;
    const int colhalf = w & 1;

    floatx4 acc[4][4] = {};   // [row-tile][gate]

    for (int phase = 0; phase < 2; ++phase) {
        const ushort_t* abase = phase ? Hb : Xb;
        const ushort_t* a0 = abase + (size_t)(bm0 + rA[0]) * IN_ + kcA[0];
        const ushort_t* a1 = abase + (size_t)(bm0 + rA[1]) * IN_ + kcA[1];
        const ushort_t* a2 = abase + (size_t)(bm0 + rA[2]) * IN_ + kcA[2];
        const ushort_t* a3 = abase + (size_t)(bm0 + rA[3]) * IN_ + kcA[3];
        const ushort_t* b0 = phase ? whp[0] : wxp[0];
        const ushort_t* b1 = phase ? whp[1] : wxp[1];
        const ushort_t* b2 = phase ? whp[2] : wxp[2];
        const ushort_t* b3 = phase ? whp[3] : wxp[3];
        for (int k0 = 0; k0 < 1024; k0 += 64) {
            gll16(a0, ldsA[0]); gll16(a1, ldsA[1]);
            gll16(a2, ldsA[2]); gll16(a3, ldsA[3]);
            gll16(b0, ldsB[0]); gll16(b1, ldsB[1]);
            gll16(b2, ldsB[2]); gll16(b3, ldsB[3]);
            a0 += 64; a1 += 64; a2 += 64; a3 += 64;
            b0 += 64; b1 += 64; b2 += 64; b3 += 64;
            __syncthreads();   // vmcnt(0) drain -> DMA complete

            #pragma unroll
            for (int ks = 0; ks < 2; ++ks) {
                short8 af[4], bfr[4];
                #pragma unroll
                for (int rt = 0; rt < 4; ++rt) {
                    const int r = rowbase + rt * 16 + lr;
                    const int p = (ks * 4 + lk) ^ (r & 7);
                    af[rt] = *(const short8*)(&As[r * 64 + p * 8]);
                }
                #pragma unroll
                for (int ct = 0; ct < 4; ++ct) {
                    const int v = colhalf * 64 + ct * 16 + lr;
                    const int p = (ks * 4 + lk) ^ (v & 7);
                    bfr[ct] = *(const short8*)(&Bs[v * 64 + p * 8]);
                }
                #pragma unroll
                for (int rt = 0; rt < 4; ++rt)
                    #pragma unroll
                    for (int ct = 0; ct < 4; ++ct)
                        acc[rt][ct] = __builtin_amdgcn_mfma_f32_16x16x32_bf16(
                            af[rt], bfr[ct], acc[rt][ct], 0, 0, 0);
            }
            __syncthreads();   // frag reads done before next DMA overwrite
        }
    }

    // ---- epilogue: 4 gates live in acc[rt][0..3], same lane/reg ----
    const int j = j0 + colhalf * 16 + lr;
    const float bi = Bi[j], bff = Bf[j], bg = Bg[j], bo = Bo[j];

    #pragma unroll
    for (int rt = 0; rt < 4; ++rt) {
        #pragma unroll
        for (int reg = 0; reg < 4; ++reg) {
            const int m = bm0 + rowbase + rt * 16 + lk * 4 + reg;
            const float zi = acc[rt][0][reg] + bi;
            const float zf = acc[rt][1][reg] + bff;
            const float zg = acc[rt][2][reg] + bg;
            const float zo = acc[rt][3][reg] + bo;
            const float ig = sigmoid_(zi);
            const float fg = sigmoid_(zf);
            const float gg = tanh_(zg);
            const float og = sigmoid_(zo);
            const float cp = Cprev[(size_t)m * H_ + j];
            const float cn = fg * cp + ig * gg;
            const float hn = og * tanh_(cn);
            Out[(size_t)m * H_ + j] = hn;                             // h_next (f32)
            Out[(size_t)B_ * H_ + (size_t)m * H_ + j] = cn;           // c_next (f32)
        }
    }
}

extern "C" void kernel_launch(void* const* d_in, const int* in_sizes, int n_in,
                              void* d_out, int out_size, void* d_ws, size_t ws_size,
                              hipStream_t stream)
{
    (void)in_sizes; (void)n_in; (void)out_size; (void)ws_size;
    const float* X   = (const float*)d_in[0];
    const float* Hin = (const float*)d_in[1];
    const float* Cp  = (const float*)d_in[2];
    const float* Wfx = (const float*)d_in[3];
    const float* Bf  = (const float*)d_in[4];
    const float* Wfh = (const float*)d_in[5];
    const float* Wix = (const float*)d_in[6];
    const float* Bi  = (const float*)d_in[7];
    const float* Wih = (const float*)d_in[8];
    const float* Wgx = (const float*)d_in[9];
    const float* Bg  = (const float*)d_in[10];
    const float* Wgh = (const float*)d_in[11];
    const float* Wox = (const float*)d_in[12];
    const float* Bo  = (const float*)d_in[13];
    const float* Woh = (const float*)d_in[14];
    float* Out = (float*)d_out;
    ushort_t* ws  = (ushort_t*)d_ws;

    // prep: f32 -> bf16 (x, h, 8 weights) into ws
    cvt_kernel<<<dim3(12288), dim3(256), 0, stream>>>(
        X, Hin, Wix, Wfx, Wgx, Wox, Wih, Wfh, Wgh, Woh, ws);

    dim3 grid(H_ / 32, B_ / 128);   // 32 x 64 = 2048 blocks
    lstm_cell_kernel<<<grid, dim3(256), 0, stream>>>(
        ws + WS_XB, ws + WS_HB, ws + WS_WB,
        Cp, Bi, Bf, Bg, Bo, Out);
}